// Round 3
// baseline (2041.822 us; speedup 1.0000x reference)
//
#include <hip/hip_runtime.h>
#include <stdint.h>

// Problem constants (fixed by the reference)
#define N_NODES 100000
#define D_FEAT  128
#define E_EDGES 1600000
#define ACMC    4
#define CCH     128
#define C2CH    256
#define KKEEP   70000     // ceil(0.7 * N)
#define MSORT   131072    // 2^17 >= N, bitonic size

typedef unsigned int u32;
typedef unsigned long long u64;
typedef unsigned short u16;

__device__ __forceinline__ float gelu_exact(float v){
    return 0.5f * v * (1.0f + erff(v * 0.70710678118654752440f));
}

// ---------------- Stage 1: h1 = gelu(x @ Wd_root.T + bd)  [N,4] ----------------
// One wave per node: lane reads float2 of x-row (512B/row coalesced), 4 dots via shuffle.
__global__ __launch_bounds__(256) void k_h1(const float* __restrict__ x,
                                            const float* __restrict__ Wd,
                                            const float* __restrict__ bd,
                                            float* __restrict__ h1) {
    int tid = threadIdx.x;
    int wid = tid >> 6, lane = tid & 63;
    int node = blockIdx.x * 4 + wid;
    if (node >= N_NODES) return;
    const float2* xr = (const float2*)(x + (size_t)node * D_FEAT);  // 128 f32 = 64 float2
    float2 v = xr[lane];
    const float2* wd = (const float2*)Wd;
    float s[4];
    #pragma unroll
    for (int j = 0; j < 4; j++) {
        float2 w = wd[j * 64 + lane];
        s[j] = v.x * w.x + v.y * w.y;
    }
    #pragma unroll
    for (int off = 32; off > 0; off >>= 1) {
        #pragma unroll
        for (int j = 0; j < 4; j++) s[j] += __shfl_xor(s[j], off);
    }
    if (lane == 0) {
        float4 o;
        o.x = gelu_exact(s[0] + bd[0]);
        o.y = gelu_exact(s[1] + bd[1]);
        o.z = gelu_exact(s[2] + bd[2]);
        o.w = gelu_exact(s[3] + bd[3]);
        ((float4*)h1)[node] = o;
    }
}

// ---------------- Stage 2: aggr1[dst] += h1[src]  (4ch scatter) ----------------
__global__ __launch_bounds__(256) void k_aggr1(const int* __restrict__ ei,
                                               const float* __restrict__ h1,
                                               float* __restrict__ aggr1) {
    int e = blockIdx.x * blockDim.x + threadIdx.x;
    if (e >= E_EDGES) return;
    int s = ei[e], d = ei[E_EDGES + e];
    float4 hv = ((const float4*)h1)[s];
    atomicAdd(&aggr1[d * 4 + 0], hv.x);
    atomicAdd(&aggr1[d * 4 + 1], hv.y);
    atomicAdd(&aggr1[d * 4 + 2], hv.z);
    atomicAdd(&aggr1[d * 4 + 3], hv.w);
}

// ---------------- Stage 3: h = gelu(aggr1@Wi_rel.T + bi + h1@Wi_root.T); score ----------------
// One block (128 threads) per node; thread = output channel.
__global__ __launch_bounds__(128) void k_h_score(const float* __restrict__ aggr1,
                                                 const float* __restrict__ h1,
                                                 const float* __restrict__ Wi_rel,
                                                 const float* __restrict__ bi,
                                                 const float* __restrict__ Wi_root,
                                                 const float* __restrict__ p,
                                                 float* __restrict__ h,
                                                 float* __restrict__ score) {
    int node = blockIdx.x;
    int c = threadIdx.x;
    float4 ag = ((const float4*)aggr1)[node];
    float4 hv = ((const float4*)h1)[node];
    float4 wr = ((const float4*)Wi_rel)[c];    // row c: 4 f32
    float4 wo = ((const float4*)Wi_root)[c];
    float val = ag.x * wr.x + ag.y * wr.y + ag.z * wr.z + ag.w * wr.w
              + hv.x * wo.x + hv.y * wo.y + hv.z * wo.z + hv.w * wo.w
              + bi[c];
    float g = gelu_exact(val);
    h[(size_t)node * CCH + c] = g;
    float pc = p[c];
    float hp = g * pc, pp = pc * pc;
    #pragma unroll
    for (int off = 32; off > 0; off >>= 1) {
        hp += __shfl_xor(hp, off);
        pp += __shfl_xor(pp, off);
    }
    __shared__ float sh[2], sp[2];
    int wid = c >> 6, lane = c & 63;
    if (lane == 0) { sh[wid] = hp; sp[wid] = pp; }
    __syncthreads();
    if (c == 0) {
        float H = sh[0] + sh[1], P = sp[0] + sp[1];
        score[node] = tanhf(H / sqrtf(P));
    }
}

// ---------------- Stage 4: sort keys = (~sortable(score))<<32 | idx, ascending ----------------
// => score descending, index ascending on ties (matches jax.lax.top_k).
__global__ __launch_bounds__(256) void k_keys(const float* __restrict__ score,
                                              u64* __restrict__ keys) {
    int i = blockIdx.x * blockDim.x + threadIdx.x;
    if (i >= MSORT) return;
    if (i < N_NODES) {
        u32 u = __float_as_uint(score[i]);
        u32 asc = (u & 0x80000000u) ? ~u : (u | 0x80000000u); // monotone float->uint
        keys[i] = (((u64)(~asc)) << 32) | (u32)i;
    } else {
        keys[i] = 0xFFFFFFFFFFFFFFFFull;  // pad sorts to the end
    }
}

__global__ __launch_bounds__(1024) void bitonic_local(u64* __restrict__ keys,
                                                      u32 kLo, u32 kHi) {
    __shared__ u64 s[2048];
    u32 base = blockIdx.x * 2048;
    u32 t = threadIdx.x;
    s[t] = keys[base + t];
    s[t + 1024] = keys[base + t + 1024];
    __syncthreads();
    for (u32 k = kLo; k <= kHi; k <<= 1) {
        u32 jstart = (k >> 1) < 1024u ? (k >> 1) : 1024u;
        for (u32 j = jstart; j >= 1; j >>= 1) {
            u32 i = ((t & ~(j - 1)) << 1) | (t & (j - 1));
            u32 l = i + j;
            bool up = (((base + i) & k) == 0);
            u64 av = s[i], bv = s[l];
            if ((av > bv) == up) { s[i] = bv; s[l] = av; }
            __syncthreads();
        }
    }
    keys[base + t] = s[t];
    keys[base + t + 1024] = s[t + 1024];
}

__global__ __launch_bounds__(256) void bitonic_global(u64* __restrict__ keys,
                                                      u32 j, u32 k) {
    u32 i = blockIdx.x * blockDim.x + threadIdx.x;
    if (i >= MSORT) return;
    u32 l = i ^ j;
    if (l > i) {
        bool up = ((i & k) == 0);
        u64 av = keys[i], bv = keys[l];
        if ((av > bv) == up) { keys[i] = bv; keys[l] = av; }
    }
}

__global__ __launch_bounds__(256) void k_rank(const u64* __restrict__ keys,
                                              int* __restrict__ rank) {
    int i = blockIdx.x * blockDim.x + threadIdx.x;
    if (i >= N_NODES) return;
    u32 n = (u32)(keys[i] & 0xFFFFFFFFu);
    rank[n] = i;
}

// ---------------- Stage 5a: aggr2[rank[d]] += h[s]*score[s] over valid edges ----------------
__global__ __launch_bounds__(256) void k_conv1(const int* __restrict__ ei,
                                               const int* __restrict__ rank,
                                               const float* __restrict__ score,
                                               const float* __restrict__ h,
                                               float* __restrict__ aggr2) {
    int tid = threadIdx.x;
    int wid = tid >> 6, lane = tid & 63;
    int e = blockIdx.x * 4 + wid;
    if (e >= E_EDGES) return;
    int s = ei[e], d = ei[E_EDGES + e];
    int rs = rank[s], rd = rank[d];
    if (rs >= KKEEP || rd >= KKEEP) return;
    float scl = score[s];
    float2 v = ((const float2*)(h + (size_t)s * CCH))[lane];
    float* dst = aggr2 + (size_t)rd * CCH + lane * 2;
    atomicAdd(dst, v.x * scl);
    atomicAdd(dst + 1, v.y * scl);
}

// ---------------- Stage 5b+6: h2 = gelu(aggr2@W1_rel.T + b1 + hp@W1_root.T); mod-3 pool ----------------
// 8 nodes per block, thread = output channel c2 of 256. Rows staged in LDS (broadcast reads).
__global__ __launch_bounds__(256) void k_h2pool(const float* __restrict__ aggr2,
                                                const float* __restrict__ h,
                                                const float* __restrict__ score,
                                                const int* __restrict__ rank,
                                                const float* __restrict__ W1_rel,
                                                const float* __restrict__ b1,
                                                const float* __restrict__ W1_root,
                                                float* __restrict__ pooled) {
    __shared__ float a2[8][128];
    __shared__ float hh[8][128];
    __shared__ float ssc[8];
    __shared__ int   srk[8];
    int tid = threadIdx.x;
    int base = blockIdx.x * 8;
    if (tid < 8) {
        int node = base + tid;
        srk[tid] = (node < N_NODES) ? rank[node] : KKEEP;
        ssc[tid] = (node < N_NODES) ? score[node] : 0.0f;
    }
    __syncthreads();
    #pragma unroll
    for (int it = 0; it < 4; it++) {
        int idx = it * 256 + tid;        // 0..1023
        int i = idx >> 7, c = idx & 127;
        int node = base + i;
        int r = srk[i];
        a2[i][c] = (r < KKEEP) ? aggr2[(size_t)r * 128 + c] : 0.0f;
        hh[i][c] = (node < N_NODES) ? h[(size_t)node * 128 + c] : 0.0f;
    }
    __syncthreads();
    int c2 = tid;
    const float2* wr = (const float2*)(W1_rel + (size_t)c2 * 128);   // row c2: 128 f32
    const float2* wo = (const float2*)(W1_root + (size_t)c2 * 128);
    float accA[8] = {0,0,0,0,0,0,0,0};
    float accH[8] = {0,0,0,0,0,0,0,0};
    for (int cc = 0; cc < 64; cc++) {
        float2 wa = wr[cc];
        float2 wb = wo[cc];
        int c = cc * 2;
        #pragma unroll
        for (int i = 0; i < 8; i++) {
            accA[i] += a2[i][c] * wa.x + a2[i][c + 1] * wa.y;
            accH[i] += hh[i][c] * wb.x + hh[i][c + 1] * wb.y;
        }
    }
    float bc = b1[c2];
    float p0 = 0.0f, p1 = 0.0f, p2 = 0.0f;
    #pragma unroll
    for (int i = 0; i < 8; i++) {
        int r = srk[i];
        if (r < KKEEP) {
            float g = gelu_exact(accA[i] + bc + ssc[i] * accH[i]);
            int ci = r % 3;
            if (ci == 0) p0 += g; else if (ci == 1) p1 += g; else p2 += g;
        }
    }
    if (p0 != 0.0f) atomicAdd(&pooled[0 * 256 + c2], p0);
    if (p1 != 0.0f) atomicAdd(&pooled[1 * 256 + c2], p1);
    if (p2 != 0.0f) atomicAdd(&pooled[2 * 256 + c2], p2);
}

// ---------------- Stage 7: out = (pooled/counts).flatten() @ Wo.T + bo ----------------
// Output is float32 (reference output dtype): plain f32 store.
__global__ __launch_bounds__(768) void k_out(const float* __restrict__ pooled,
                                             const float* __restrict__ Wo,
                                             const float* __restrict__ bo,
                                             float* __restrict__ out) {
    __shared__ float red[12];
    int t = threadIdx.x;   // 768 threads
    int ci = t >> 8;
    float cnt = (ci == 0) ? 23334.0f : 23333.0f;  // #ranks == ci (mod 3), K=70000
    float acc = (pooled[t] / cnt) * Wo[t];
    #pragma unroll
    for (int off = 32; off > 0; off >>= 1) acc += __shfl_xor(acc, off);
    int wid = t >> 6, lane = t & 63;
    if (lane == 0) red[wid] = acc;
    __syncthreads();
    if (t == 0) {
        float s = 0.0f;
        #pragma unroll
        for (int w = 0; w < 12; w++) s += red[w];
        out[0] = s + bo[0];
    }
}

extern "C" void kernel_launch(void* const* d_in, const int* in_sizes, int n_in,
                              void* d_out, int out_size, void* d_ws, size_t ws_size,
                              hipStream_t stream) {
    const float* x       = (const float*)d_in[0];
    const int*   ei      = (const int*)d_in[1];
    const float* Wd      = (const float*)d_in[2];
    const float* bd      = (const float*)d_in[3];
    const float* Wi_rel  = (const float*)d_in[4];
    const float* bi      = (const float*)d_in[5];
    const float* Wi_root = (const float*)d_in[6];
    const float* p       = (const float*)d_in[7];
    const float* W1_rel  = (const float*)d_in[8];
    const float* b1      = (const float*)d_in[9];
    const float* W1_root = (const float*)d_in[10];
    const float* Wo      = (const float*)d_in[11];
    const float* bo      = (const float*)d_in[12];

    // workspace layout (~92 MB total)
    char* ws = (char*)d_ws;
    size_t off = 0;
    auto alloc = [&](size_t bytes) -> void* {
        void* ptr = ws + off;
        off += (bytes + 255) & ~(size_t)255;
        return ptr;
    };
    float* h1     = (float*)alloc((size_t)N_NODES * 4 * sizeof(float));
    float* aggr1  = (float*)alloc((size_t)N_NODES * 4 * sizeof(float));
    float* h      = (float*)alloc((size_t)N_NODES * CCH * sizeof(float));
    float* score  = (float*)alloc((size_t)N_NODES * sizeof(float));
    u64*   keys   = (u64*)alloc((size_t)MSORT * sizeof(u64));
    int*   rank   = (int*)alloc((size_t)N_NODES * sizeof(int));
    float* aggr2  = (float*)alloc((size_t)KKEEP * CCH * sizeof(float));
    float* pooled = (float*)alloc(768 * sizeof(float));
    (void)ws_size; (void)in_sizes; (void)n_in; (void)out_size;

    hipMemsetAsync(aggr1, 0, (size_t)N_NODES * 4 * sizeof(float), stream);
    hipMemsetAsync(aggr2, 0, (size_t)KKEEP * CCH * sizeof(float), stream);
    hipMemsetAsync(pooled, 0, 768 * sizeof(float), stream);

    k_h1<<<N_NODES / 4, 256, 0, stream>>>(x, Wd, bd, h1);
    k_aggr1<<<(E_EDGES + 255) / 256, 256, 0, stream>>>(ei, h1, aggr1);
    k_h_score<<<N_NODES, 128, 0, stream>>>(aggr1, h1, Wi_rel, bi, Wi_root, p, h, score);
    k_keys<<<MSORT / 256, 256, 0, stream>>>(score, keys);

    bitonic_local<<<MSORT / 2048, 1024, 0, stream>>>(keys, 2, 2048);
    for (u32 k = 4096; k <= MSORT; k <<= 1) {
        for (u32 j = k >> 1; j >= 2048; j >>= 1)
            bitonic_global<<<MSORT / 256, 256, 0, stream>>>(keys, j, k);
        bitonic_local<<<MSORT / 2048, 1024, 0, stream>>>(keys, k, k);
    }
    k_rank<<<(N_NODES + 255) / 256, 256, 0, stream>>>(keys, rank);

    k_conv1<<<E_EDGES / 4, 256, 0, stream>>>(ei, rank, score, h, aggr2);
    k_h2pool<<<(N_NODES + 7) / 8, 256, 0, stream>>>(aggr2, h, score, rank,
                                                    W1_rel, b1, W1_root, pooled);
    k_out<<<1, 768, 0, stream>>>(pooled, Wo, bo, (float*)d_out);
}

// Round 4
// 1546.797 us; speedup vs baseline: 1.3200x; 1.3200x over previous
//
#include <hip/hip_runtime.h>
#include <stdint.h>

// Problem constants (fixed by the reference)
#define N_NODES 100000
#define D_FEAT  128
#define E_EDGES 1600000
#define ACMC    4
#define CCH     128
#define C2CH    256
#define KKEEP   70000     // ceil(0.7 * N)
#define MSORT   131072    // 2^17 >= N, bitonic size

typedef unsigned int u32;
typedef unsigned long long u64;
typedef unsigned short u16;

__device__ __forceinline__ float gelu_exact(float v){
    return 0.5f * v * (1.0f + erff(v * 0.70710678118654752440f));
}

// ---------------- Stage 1: h1 = gelu(x @ Wd_root.T + bd)  [N,4] ----------------
__global__ __launch_bounds__(256) void k_h1(const float* __restrict__ x,
                                            const float* __restrict__ Wd,
                                            const float* __restrict__ bd,
                                            float* __restrict__ h1) {
    int tid = threadIdx.x;
    int wid = tid >> 6, lane = tid & 63;
    int node = blockIdx.x * 4 + wid;
    if (node >= N_NODES) return;
    const float2* xr = (const float2*)(x + (size_t)node * D_FEAT);
    float2 v = xr[lane];
    const float2* wd = (const float2*)Wd;
    float s[4];
    #pragma unroll
    for (int j = 0; j < 4; j++) {
        float2 w = wd[j * 64 + lane];
        s[j] = v.x * w.x + v.y * w.y;
    }
    #pragma unroll
    for (int off = 32; off > 0; off >>= 1) {
        #pragma unroll
        for (int j = 0; j < 4; j++) s[j] += __shfl_xor(s[j], off);
    }
    if (lane == 0) {
        float4 o;
        o.x = gelu_exact(s[0] + bd[0]);
        o.y = gelu_exact(s[1] + bd[1]);
        o.z = gelu_exact(s[2] + bd[2]);
        o.w = gelu_exact(s[3] + bd[3]);
        ((float4*)h1)[node] = o;
    }
}

// ---------------- Stage 2: aggr1[dst] += h1[src]  (4ch scatter) ----------------
__global__ __launch_bounds__(256) void k_aggr1(const int* __restrict__ ei,
                                               const float* __restrict__ h1,
                                               float* __restrict__ aggr1) {
    int e = blockIdx.x * blockDim.x + threadIdx.x;
    if (e >= E_EDGES) return;
    int s = ei[e], d = ei[E_EDGES + e];
    float4 hv = ((const float4*)h1)[s];
    atomicAdd(&aggr1[d * 4 + 0], hv.x);
    atomicAdd(&aggr1[d * 4 + 1], hv.y);
    atomicAdd(&aggr1[d * 4 + 2], hv.z);
    atomicAdd(&aggr1[d * 4 + 3], hv.w);
}

// ---------------- Stage 3: h = gelu(aggr1@Wi_rel.T + bi + h1@Wi_root.T); score ----------------
__global__ __launch_bounds__(128) void k_h_score(const float* __restrict__ aggr1,
                                                 const float* __restrict__ h1,
                                                 const float* __restrict__ Wi_rel,
                                                 const float* __restrict__ bi,
                                                 const float* __restrict__ Wi_root,
                                                 const float* __restrict__ p,
                                                 float* __restrict__ h,
                                                 float* __restrict__ score) {
    int node = blockIdx.x;
    int c = threadIdx.x;
    float4 ag = ((const float4*)aggr1)[node];
    float4 hv = ((const float4*)h1)[node];
    float4 wr = ((const float4*)Wi_rel)[c];
    float4 wo = ((const float4*)Wi_root)[c];
    float val = ag.x * wr.x + ag.y * wr.y + ag.z * wr.z + ag.w * wr.w
              + hv.x * wo.x + hv.y * wo.y + hv.z * wo.z + hv.w * wo.w
              + bi[c];
    float g = gelu_exact(val);
    h[(size_t)node * CCH + c] = g;
    float pc = p[c];
    float hp = g * pc, pp = pc * pc;
    #pragma unroll
    for (int off = 32; off > 0; off >>= 1) {
        hp += __shfl_xor(hp, off);
        pp += __shfl_xor(pp, off);
    }
    __shared__ float sh[2], sp[2];
    int wid = c >> 6, lane = c & 63;
    if (lane == 0) { sh[wid] = hp; sp[wid] = pp; }
    __syncthreads();
    if (c == 0) {
        float H = sh[0] + sh[1], P = sp[0] + sp[1];
        score[node] = tanhf(H / sqrtf(P));
    }
}

// ---------------- Stage 4: sort keys = (~sortable(score))<<32 | idx, ascending ----------------
__global__ __launch_bounds__(256) void k_keys(const float* __restrict__ score,
                                              u64* __restrict__ keys) {
    int i = blockIdx.x * blockDim.x + threadIdx.x;
    if (i >= MSORT) return;
    if (i < N_NODES) {
        u32 u = __float_as_uint(score[i]);
        u32 asc = (u & 0x80000000u) ? ~u : (u | 0x80000000u); // monotone float->uint
        keys[i] = (((u64)(~asc)) << 32) | (u32)i;
    } else {
        keys[i] = 0xFFFFFFFFFFFFFFFFull;  // pad sorts to the end
    }
}

__global__ __launch_bounds__(1024) void bitonic_local(u64* __restrict__ keys,
                                                      u32 kLo, u32 kHi) {
    __shared__ u64 s[2048];
    u32 base = blockIdx.x * 2048;
    u32 t = threadIdx.x;
    s[t] = keys[base + t];
    s[t + 1024] = keys[base + t + 1024];
    __syncthreads();
    for (u32 k = kLo; k <= kHi; k <<= 1) {
        u32 jstart = (k >> 1) < 1024u ? (k >> 1) : 1024u;
        for (u32 j = jstart; j >= 1; j >>= 1) {
            u32 i = ((t & ~(j - 1)) << 1) | (t & (j - 1));
            u32 l = i + j;
            bool up = (((base + i) & k) == 0);
            u64 av = s[i], bv = s[l];
            if ((av > bv) == up) { s[i] = bv; s[l] = av; }
            __syncthreads();
        }
    }
    keys[base + t] = s[t];
    keys[base + t + 1024] = s[t + 1024];
}

__global__ __launch_bounds__(256) void bitonic_global(u64* __restrict__ keys,
                                                      u32 j, u32 k) {
    u32 i = blockIdx.x * blockDim.x + threadIdx.x;
    if (i >= MSORT) return;
    u32 l = i ^ j;
    if (l > i) {
        bool up = ((i & k) == 0);
        u64 av = keys[i], bv = keys[l];
        if ((av > bv) == up) { keys[i] = bv; keys[l] = av; }
    }
}

// rank[node] = sorted position; noder[pos] = node (inverse permutation)
__global__ __launch_bounds__(256) void k_rank(const u64* __restrict__ keys,
                                              int* __restrict__ rank,
                                              int* __restrict__ noder) {
    int i = blockIdx.x * blockDim.x + threadIdx.x;
    if (i >= N_NODES) return;
    u32 n = (u32)(keys[i] & 0xFFFFFFFFu);
    rank[n] = i;
    noder[i] = (int)n;
}

// ---------------- Stage 5a: aggr2[rank[d]] += h[s]*score[s] over valid edges ----------------
__global__ __launch_bounds__(256) void k_conv1(const int* __restrict__ ei,
                                               const int* __restrict__ rank,
                                               const float* __restrict__ score,
                                               const float* __restrict__ h,
                                               float* __restrict__ aggr2) {
    int tid = threadIdx.x;
    int wid = tid >> 6, lane = tid & 63;
    int e = blockIdx.x * 4 + wid;
    if (e >= E_EDGES) return;
    int s = ei[e], d = ei[E_EDGES + e];
    int rs = rank[s], rd = rank[d];
    if (rs >= KKEEP || rd >= KKEEP) return;
    float scl = score[s];
    float2 v = ((const float2*)(h + (size_t)s * CCH))[lane];
    float* dst = aggr2 + (size_t)rd * CCH + lane * 2;
    atomicAdd(dst, v.x * scl);
    atomicAdd(dst + 1, v.y * scl);
}

// ---------------- Stage 5b+6: fused GEMM over ranks + mod-3 pool ----------------
// h2[r] = gelu( [aggr2[r] | h[noder[r]]*score] . [W1_rel_row | W1_root_row] + b1 )
// 32 ranks per block (weights amortized 4x vs before, no masked rows).
// Staged input tile in[32][256] f32 (32 KB LDS), fully-coalesced float4 staging.
// Compute: thread = out-channel c2, acc[32], weights streamed as float4 (1 global
// 16B load per 128 FMA), inputs via broadcast ds_read_b128 (conflict-free).
__global__ __launch_bounds__(256) void k_h2pool(const float* __restrict__ aggr2,
                                                const float* __restrict__ h,
                                                const float* __restrict__ score,
                                                const int* __restrict__ noder,
                                                const float* __restrict__ W1_rel,
                                                const float* __restrict__ b1,
                                                const float* __restrict__ W1_root,
                                                float* __restrict__ pooled) {
    __shared__ float in[32][256];
    __shared__ int   snode[32];
    __shared__ float sscl[32];
    int tid = threadIdx.x;
    int base = blockIdx.x * 32;
    if (tid < 32) {
        int r = base + tid;
        int n = (r < KKEEP) ? noder[r] : -1;
        snode[tid] = n;
        sscl[tid]  = (n >= 0) ? score[n] : 0.0f;
    }
    __syncthreads();
    // stage 32 rows x 256 f32 = 2048 float4; 8 float4 per thread, coalesced.
    #pragma unroll
    for (int it = 0; it < 8; it++) {
        int idx = it * 256 + tid;        // 0..2047 == i*64 + k4
        int i = idx >> 6, k4 = idx & 63;
        int n = snode[i];
        float4 v = make_float4(0.f, 0.f, 0.f, 0.f);
        if (n >= 0) {
            if (k4 < 32) {
                v = ((const float4*)aggr2)[(size_t)(base + i) * 32 + k4];
            } else {
                v = ((const float4*)h)[(size_t)n * 32 + (k4 - 32)];
                float s = sscl[i];
                v.x *= s; v.y *= s; v.z *= s; v.w *= s;
            }
        }
        ((float4*)in)[idx] = v;
    }
    __syncthreads();

    int c2 = tid;
    float acc[32];
    #pragma unroll
    for (int i = 0; i < 32; i++) acc[i] = 0.0f;
    const float4* wrel  = (const float4*)W1_rel  + (size_t)c2 * 32;
    const float4* wroot = (const float4*)W1_root + (size_t)c2 * 32;
    #pragma unroll 1
    for (int kk = 0; kk < 32; kk++) {
        float4 w = wrel[kk];
        #pragma unroll
        for (int i = 0; i < 32; i++) {
            float4 v = ((const float4*)&in[i][0])[kk];
            acc[i] += v.x * w.x + v.y * w.y + v.z * w.z + v.w * w.w;
        }
    }
    #pragma unroll 1
    for (int kk = 0; kk < 32; kk++) {
        float4 w = wroot[kk];
        #pragma unroll
        for (int i = 0; i < 32; i++) {
            float4 v = ((const float4*)&in[i][0])[32 + kk];
            acc[i] += v.x * w.x + v.y * w.y + v.z * w.z + v.w * w.w;
        }
    }

    float bc = b1[c2];
    float p0 = 0.f, p1 = 0.f, p2 = 0.f;
    #pragma unroll
    for (int i = 0; i < 32; i++) {
        if (snode[i] >= 0) {
            float g = gelu_exact(acc[i] + bc);
            int ci = (base + i) % 3;
            if (ci == 0) p0 += g; else if (ci == 1) p1 += g; else p2 += g;
        }
    }
    if (p0 != 0.0f) atomicAdd(&pooled[0 * 256 + c2], p0);
    if (p1 != 0.0f) atomicAdd(&pooled[1 * 256 + c2], p1);
    if (p2 != 0.0f) atomicAdd(&pooled[2 * 256 + c2], p2);
}

// ---------------- Stage 7: out = (pooled/counts).flatten() @ Wo.T + bo ----------------
__global__ __launch_bounds__(768) void k_out(const float* __restrict__ pooled,
                                             const float* __restrict__ Wo,
                                             const float* __restrict__ bo,
                                             float* __restrict__ out) {
    __shared__ float red[12];
    int t = threadIdx.x;   // 768 threads
    int ci = t >> 8;
    float cnt = (ci == 0) ? 23334.0f : 23333.0f;  // #ranks == ci (mod 3), K=70000
    float acc = (pooled[t] / cnt) * Wo[t];
    #pragma unroll
    for (int off = 32; off > 0; off >>= 1) acc += __shfl_xor(acc, off);
    int wid = t >> 6, lane = t & 63;
    if (lane == 0) red[wid] = acc;
    __syncthreads();
    if (t == 0) {
        float s = 0.0f;
        #pragma unroll
        for (int w = 0; w < 12; w++) s += red[w];
        out[0] = s + bo[0];
    }
}

extern "C" void kernel_launch(void* const* d_in, const int* in_sizes, int n_in,
                              void* d_out, int out_size, void* d_ws, size_t ws_size,
                              hipStream_t stream) {
    const float* x       = (const float*)d_in[0];
    const int*   ei      = (const int*)d_in[1];
    const float* Wd      = (const float*)d_in[2];
    const float* bd      = (const float*)d_in[3];
    const float* Wi_rel  = (const float*)d_in[4];
    const float* bi      = (const float*)d_in[5];
    const float* Wi_root = (const float*)d_in[6];
    const float* p       = (const float*)d_in[7];
    const float* W1_rel  = (const float*)d_in[8];
    const float* b1      = (const float*)d_in[9];
    const float* W1_root = (const float*)d_in[10];
    const float* Wo      = (const float*)d_in[11];
    const float* bo      = (const float*)d_in[12];

    char* ws = (char*)d_ws;
    size_t off = 0;
    auto alloc = [&](size_t bytes) -> void* {
        void* ptr = ws + off;
        off += (bytes + 255) & ~(size_t)255;
        return ptr;
    };
    float* h1     = (float*)alloc((size_t)N_NODES * 4 * sizeof(float));
    float* aggr1  = (float*)alloc((size_t)N_NODES * 4 * sizeof(float));
    float* h      = (float*)alloc((size_t)N_NODES * CCH * sizeof(float));
    float* score  = (float*)alloc((size_t)N_NODES * sizeof(float));
    u64*   keys   = (u64*)alloc((size_t)MSORT * sizeof(u64));
    int*   rank   = (int*)alloc((size_t)N_NODES * sizeof(int));
    int*   noder  = (int*)alloc((size_t)N_NODES * sizeof(int));
    float* aggr2  = (float*)alloc((size_t)KKEEP * CCH * sizeof(float));
    float* pooled = (float*)alloc(768 * sizeof(float));
    (void)ws_size; (void)in_sizes; (void)n_in; (void)out_size;

    hipMemsetAsync(aggr1, 0, (size_t)N_NODES * 4 * sizeof(float), stream);
    hipMemsetAsync(aggr2, 0, (size_t)KKEEP * CCH * sizeof(float), stream);
    hipMemsetAsync(pooled, 0, 768 * sizeof(float), stream);

    k_h1<<<N_NODES / 4, 256, 0, stream>>>(x, Wd, bd, h1);
    k_aggr1<<<(E_EDGES + 255) / 256, 256, 0, stream>>>(ei, h1, aggr1);
    k_h_score<<<N_NODES, 128, 0, stream>>>(aggr1, h1, Wi_rel, bi, Wi_root, p, h, score);
    k_keys<<<MSORT / 256, 256, 0, stream>>>(score, keys);

    bitonic_local<<<MSORT / 2048, 1024, 0, stream>>>(keys, 2, 2048);
    for (u32 k = 4096; k <= MSORT; k <<= 1) {
        for (u32 j = k >> 1; j >= 2048; j >>= 1)
            bitonic_global<<<MSORT / 256, 256, 0, stream>>>(keys, j, k);
        bitonic_local<<<MSORT / 2048, 1024, 0, stream>>>(keys, k, k);
    }
    k_rank<<<(N_NODES + 255) / 256, 256, 0, stream>>>(keys, rank, noder);

    k_conv1<<<E_EDGES / 4, 256, 0, stream>>>(ei, rank, score, h, aggr2);
    k_h2pool<<<(KKEEP + 31) / 32, 256, 0, stream>>>(aggr2, h, score, noder,
                                                    W1_rel, b1, W1_root, pooled);
    k_out<<<1, 768, 0, stream>>>(pooled, Wo, bo, (float*)d_out);
}

// Round 5
// 1089.009 us; speedup vs baseline: 1.8749x; 1.4204x over previous
//
#include <hip/hip_runtime.h>
#include <stdint.h>

// Problem constants (fixed by the reference)
#define N_NODES 100000
#define D_FEAT  128
#define E_EDGES 1600000
#define ACMC    4
#define CCH     128
#define C2CH    256
#define KKEEP   70000     // ceil(0.7 * N)
#define MSORT   131072    // 2^17 >= N, bitonic size

typedef unsigned int u32;
typedef unsigned long long u64;
typedef unsigned short u16;

__device__ __forceinline__ float gelu_exact(float v){
    return 0.5f * v * (1.0f + erff(v * 0.70710678118654752440f));
}

// ---------------- Stage 1: h1 = gelu(x @ Wd_root.T + bd)  [N,4] ----------------
__global__ __launch_bounds__(256) void k_h1(const float* __restrict__ x,
                                            const float* __restrict__ Wd,
                                            const float* __restrict__ bd,
                                            float* __restrict__ h1) {
    int tid = threadIdx.x;
    int wid = tid >> 6, lane = tid & 63;
    int node = blockIdx.x * 4 + wid;
    if (node >= N_NODES) return;
    const float2* xr = (const float2*)(x + (size_t)node * D_FEAT);
    float2 v = xr[lane];
    const float2* wd = (const float2*)Wd;
    float s[4];
    #pragma unroll
    for (int j = 0; j < 4; j++) {
        float2 w = wd[j * 64 + lane];
        s[j] = v.x * w.x + v.y * w.y;
    }
    #pragma unroll
    for (int off = 32; off > 0; off >>= 1) {
        #pragma unroll
        for (int j = 0; j < 4; j++) s[j] += __shfl_xor(s[j], off);
    }
    if (lane == 0) {
        float4 o;
        o.x = gelu_exact(s[0] + bd[0]);
        o.y = gelu_exact(s[1] + bd[1]);
        o.z = gelu_exact(s[2] + bd[2]);
        o.w = gelu_exact(s[3] + bd[3]);
        ((float4*)h1)[node] = o;
    }
}

// ---------------- Stage 2: aggr1[dst] += h1[src]  (4ch scatter) ----------------
__global__ __launch_bounds__(256) void k_aggr1(const int* __restrict__ ei,
                                               const float* __restrict__ h1,
                                               float* __restrict__ aggr1) {
    int e = blockIdx.x * blockDim.x + threadIdx.x;
    if (e >= E_EDGES) return;
    int s = ei[e], d = ei[E_EDGES + e];
    float4 hv = ((const float4*)h1)[s];
    atomicAdd(&aggr1[d * 4 + 0], hv.x);
    atomicAdd(&aggr1[d * 4 + 1], hv.y);
    atomicAdd(&aggr1[d * 4 + 2], hv.z);
    atomicAdd(&aggr1[d * 4 + 3], hv.w);
}

// ---------------- Stage 3: hs = gelu(...)*score; score = tanh(h.p/||p||) ----------------
// One block (128 threads) per node. Both downstream consumers (conv1 message and
// h2pool root term) use h*score, never unscaled h -> fold the scale in here.
__global__ __launch_bounds__(128) void k_h_score(const float* __restrict__ aggr1,
                                                 const float* __restrict__ h1,
                                                 const float* __restrict__ Wi_rel,
                                                 const float* __restrict__ bi,
                                                 const float* __restrict__ Wi_root,
                                                 const float* __restrict__ p,
                                                 float* __restrict__ hs,
                                                 float* __restrict__ score) {
    int node = blockIdx.x;
    int c = threadIdx.x;
    float4 ag = ((const float4*)aggr1)[node];
    float4 hv = ((const float4*)h1)[node];
    float4 wr = ((const float4*)Wi_rel)[c];
    float4 wo = ((const float4*)Wi_root)[c];
    float val = ag.x * wr.x + ag.y * wr.y + ag.z * wr.z + ag.w * wr.w
              + hv.x * wo.x + hv.y * wo.y + hv.z * wo.z + hv.w * wo.w
              + bi[c];
    float g = gelu_exact(val);
    float pc = p[c];
    float hp = g * pc, pp = pc * pc;
    #pragma unroll
    for (int off = 32; off > 0; off >>= 1) {
        hp += __shfl_xor(hp, off);
        pp += __shfl_xor(pp, off);
    }
    __shared__ float sh[2], sp[2];
    __shared__ float sscore;
    int wid = c >> 6, lane = c & 63;
    if (lane == 0) { sh[wid] = hp; sp[wid] = pp; }
    __syncthreads();
    if (c == 0) {
        float H = sh[0] + sh[1], P = sp[0] + sp[1];
        float sc = tanhf(H / sqrtf(P));
        score[node] = sc;
        sscore = sc;
    }
    __syncthreads();
    hs[(size_t)node * CCH + c] = g * sscore;
}

// ---------------- Stage 4: sort keys = (~sortable(score))<<32 | idx, ascending ----------------
__global__ __launch_bounds__(256) void k_keys(const float* __restrict__ score,
                                              u64* __restrict__ keys) {
    int i = blockIdx.x * blockDim.x + threadIdx.x;
    if (i >= MSORT) return;
    if (i < N_NODES) {
        u32 u = __float_as_uint(score[i]);
        u32 asc = (u & 0x80000000u) ? ~u : (u | 0x80000000u); // monotone float->uint
        keys[i] = (((u64)(~asc)) << 32) | (u32)i;
    } else {
        keys[i] = 0xFFFFFFFFFFFFFFFFull;  // pad sorts to the end
    }
}

__global__ __launch_bounds__(1024) void bitonic_local(u64* __restrict__ keys,
                                                      u32 kLo, u32 kHi) {
    __shared__ u64 s[2048];
    u32 base = blockIdx.x * 2048;
    u32 t = threadIdx.x;
    s[t] = keys[base + t];
    s[t + 1024] = keys[base + t + 1024];
    __syncthreads();
    for (u32 k = kLo; k <= kHi; k <<= 1) {
        u32 jstart = (k >> 1) < 1024u ? (k >> 1) : 1024u;
        for (u32 j = jstart; j >= 1; j >>= 1) {
            u32 i = ((t & ~(j - 1)) << 1) | (t & (j - 1));
            u32 l = i + j;
            bool up = (((base + i) & k) == 0);
            u64 av = s[i], bv = s[l];
            if ((av > bv) == up) { s[i] = bv; s[l] = av; }
            __syncthreads();
        }
    }
    keys[base + t] = s[t];
    keys[base + t + 1024] = s[t + 1024];
}

__global__ __launch_bounds__(256) void bitonic_global(u64* __restrict__ keys,
                                                      u32 j, u32 k) {
    u32 i = blockIdx.x * blockDim.x + threadIdx.x;
    if (i >= MSORT) return;
    u32 l = i ^ j;
    if (l > i) {
        bool up = ((i & k) == 0);
        u64 av = keys[i], bv = keys[l];
        if ((av > bv) == up) { keys[i] = bv; keys[l] = av; }
    }
}

// rank[node] = sorted position; noder[pos] = node (inverse permutation)
__global__ __launch_bounds__(256) void k_rank(const u64* __restrict__ keys,
                                              int* __restrict__ rank,
                                              int* __restrict__ noder) {
    int i = blockIdx.x * blockDim.x + threadIdx.x;
    if (i >= N_NODES) return;
    u32 n = (u32)(keys[i] & 0xFFFFFFFFu);
    rank[n] = i;
    noder[i] = (int)n;
}

// ---------------- Stage 5a (CSR build): degree histogram over dst ranks ----------------
__global__ __launch_bounds__(256) void k_deg(const int* __restrict__ ei,
                                             const int* __restrict__ rank,
                                             int* __restrict__ deg) {
    int e = blockIdx.x * blockDim.x + threadIdx.x;
    if (e >= E_EDGES) return;
    int s = ei[e], d = ei[E_EDGES + e];
    int rs = rank[s], rd = rank[d];
    if (rs >= KKEEP || rd >= KKEEP) return;
    atomicAdd(&deg[rd], 1);
}

// Exclusive scan of deg[0..KKEEP) -> off[0..KKEEP], single block of 1024 threads.
__global__ __launch_bounds__(1024) void k_scan(const int* __restrict__ deg,
                                               int* __restrict__ off) {
    const int T = 1024;
    const int chunk = (KKEEP + T - 1) / T;   // 69
    int t = threadIdx.x;
    int begin = t * chunk;
    int end = begin + chunk; if (end > KKEEP) end = KKEEP;
    int sum = 0;
    for (int i = begin; i < end; i++) sum += deg[i];
    int lane = t & 63, wid = t >> 6;
    // inclusive wave scan of per-thread sums
    int v = sum;
    #pragma unroll
    for (int o = 1; o < 64; o <<= 1) {
        int u = __shfl_up(v, o);
        if (lane >= o) v += u;
    }
    __shared__ int wtot[16];
    __shared__ int wbase[17];
    if (lane == 63) wtot[wid] = v;
    __syncthreads();
    if (t == 0) {
        int run = 0;
        #pragma unroll
        for (int w = 0; w < 16; w++) { wbase[w] = run; run += wtot[w]; }
        wbase[16] = run;
        off[KKEEP] = run;    // total valid edges
    }
    __syncthreads();
    int run = wbase[wid] + (v - sum);   // exclusive prefix for this thread
    for (int i = begin; i < end; i++) { off[i] = run; run += deg[i]; }
}

// Fill CSR slots: slot[off[rd] + cursor[rd]++] = src node id
__global__ __launch_bounds__(256) void k_fill(const int* __restrict__ ei,
                                              const int* __restrict__ rank,
                                              const int* __restrict__ off,
                                              int* __restrict__ cursor,
                                              int* __restrict__ slot) {
    int e = blockIdx.x * blockDim.x + threadIdx.x;
    if (e >= E_EDGES) return;
    int s = ei[e], d = ei[E_EDGES + e];
    int rs = rank[s], rd = rank[d];
    if (rs >= KKEEP || rd >= KKEEP) return;
    int pos = atomicAdd(&cursor[rd], 1);
    slot[off[rd] + pos] = s;
}

// ---------------- Stage 5a (gather): aggr2[rd] = sum_{e in CSR[rd]} hs[src(e)] ----------------
// One wave per dst rank; lane owns float2 of channels. 512B coalesced row reads,
// one plain 512B store per row. No float atomics.
__global__ __launch_bounds__(256) void k_gather(const int* __restrict__ off,
                                                const int* __restrict__ slot,
                                                const float* __restrict__ hs,
                                                float* __restrict__ aggr2) {
    int tid = threadIdx.x;
    int wid = tid >> 6, lane = tid & 63;
    int rd = blockIdx.x * 4 + wid;
    if (rd >= KKEEP) return;
    int i = off[rd], end = off[rd + 1];
    float2 acc = make_float2(0.f, 0.f);
    for (; i + 1 < end; i += 2) {
        int sa = slot[i], sb = slot[i + 1];
        float2 va = ((const float2*)(hs + (size_t)sa * CCH))[lane];
        float2 vb = ((const float2*)(hs + (size_t)sb * CCH))[lane];
        acc.x += va.x + vb.x;
        acc.y += va.y + vb.y;
    }
    if (i < end) {
        int sa = slot[i];
        float2 va = ((const float2*)(hs + (size_t)sa * CCH))[lane];
        acc.x += va.x;
        acc.y += va.y;
    }
    ((float2*)(aggr2 + (size_t)rd * CCH))[lane] = acc;
}

// ---------------- Stage 5b+6: fused GEMM over ranks + mod-3 pool ----------------
// h2[r] = gelu( [aggr2[r] | hs[noder[r]]] . [W1_rel_row | W1_root_row] + b1 )
__global__ __launch_bounds__(256) void k_h2pool(const float* __restrict__ aggr2,
                                                const float* __restrict__ hs,
                                                const int* __restrict__ noder,
                                                const float* __restrict__ W1_rel,
                                                const float* __restrict__ b1,
                                                const float* __restrict__ W1_root,
                                                float* __restrict__ pooled) {
    __shared__ float in[32][256];
    __shared__ int   snode[32];
    int tid = threadIdx.x;
    int base = blockIdx.x * 32;
    if (tid < 32) {
        int r = base + tid;
        snode[tid] = (r < KKEEP) ? noder[r] : -1;
    }
    __syncthreads();
    // stage 32 rows x 256 f32 = 2048 float4; 8 float4 per thread, coalesced.
    #pragma unroll
    for (int it = 0; it < 8; it++) {
        int idx = it * 256 + tid;        // 0..2047 == i*64 + k4
        int i = idx >> 6, k4 = idx & 63;
        int n = snode[i];
        float4 v = make_float4(0.f, 0.f, 0.f, 0.f);
        if (n >= 0) {
            if (k4 < 32) {
                v = ((const float4*)aggr2)[(size_t)(base + i) * 32 + k4];
            } else {
                v = ((const float4*)hs)[(size_t)n * 32 + (k4 - 32)];
            }
        }
        ((float4*)in)[idx] = v;
    }
    __syncthreads();

    int c2 = tid;
    float acc[32];
    #pragma unroll
    for (int i = 0; i < 32; i++) acc[i] = 0.0f;
    const float4* wrel  = (const float4*)W1_rel  + (size_t)c2 * 32;
    const float4* wroot = (const float4*)W1_root + (size_t)c2 * 32;
    #pragma unroll 1
    for (int kk = 0; kk < 32; kk++) {
        float4 w = wrel[kk];
        #pragma unroll
        for (int i = 0; i < 32; i++) {
            float4 v = ((const float4*)&in[i][0])[kk];
            acc[i] += v.x * w.x + v.y * w.y + v.z * w.z + v.w * w.w;
        }
    }
    #pragma unroll 1
    for (int kk = 0; kk < 32; kk++) {
        float4 w = wroot[kk];
        #pragma unroll
        for (int i = 0; i < 32; i++) {
            float4 v = ((const float4*)&in[i][0])[32 + kk];
            acc[i] += v.x * w.x + v.y * w.y + v.z * w.z + v.w * w.w;
        }
    }

    float bc = b1[c2];
    float p0 = 0.f, p1 = 0.f, p2 = 0.f;
    #pragma unroll
    for (int i = 0; i < 32; i++) {
        if (snode[i] >= 0) {
            float g = gelu_exact(acc[i] + bc);
            int ci = (base + i) % 3;
            if (ci == 0) p0 += g; else if (ci == 1) p1 += g; else p2 += g;
        }
    }
    if (p0 != 0.0f) atomicAdd(&pooled[0 * 256 + c2], p0);
    if (p1 != 0.0f) atomicAdd(&pooled[1 * 256 + c2], p1);
    if (p2 != 0.0f) atomicAdd(&pooled[2 * 256 + c2], p2);
}

// ---------------- Stage 7: out = (pooled/counts).flatten() @ Wo.T + bo ----------------
__global__ __launch_bounds__(768) void k_out(const float* __restrict__ pooled,
                                             const float* __restrict__ Wo,
                                             const float* __restrict__ bo,
                                             float* __restrict__ out) {
    __shared__ float red[12];
    int t = threadIdx.x;   // 768 threads
    int ci = t >> 8;
    float cnt = (ci == 0) ? 23334.0f : 23333.0f;  // #ranks == ci (mod 3), K=70000
    float acc = (pooled[t] / cnt) * Wo[t];
    #pragma unroll
    for (int off = 32; off > 0; off >>= 1) acc += __shfl_xor(acc, off);
    int wid = t >> 6, lane = t & 63;
    if (lane == 0) red[wid] = acc;
    __syncthreads();
    if (t == 0) {
        float s = 0.0f;
        #pragma unroll
        for (int w = 0; w < 12; w++) s += red[w];
        out[0] = s + bo[0];
    }
}

extern "C" void kernel_launch(void* const* d_in, const int* in_sizes, int n_in,
                              void* d_out, int out_size, void* d_ws, size_t ws_size,
                              hipStream_t stream) {
    const float* x       = (const float*)d_in[0];
    const int*   ei      = (const int*)d_in[1];
    const float* Wd      = (const float*)d_in[2];
    const float* bd      = (const float*)d_in[3];
    const float* Wi_rel  = (const float*)d_in[4];
    const float* bi      = (const float*)d_in[5];
    const float* Wi_root = (const float*)d_in[6];
    const float* p       = (const float*)d_in[7];
    const float* W1_rel  = (const float*)d_in[8];
    const float* b1      = (const float*)d_in[9];
    const float* W1_root = (const float*)d_in[10];
    const float* Wo      = (const float*)d_in[11];
    const float* bo      = (const float*)d_in[12];

    char* ws = (char*)d_ws;
    size_t off_b = 0;
    auto alloc = [&](size_t bytes) -> void* {
        void* ptr = ws + off_b;
        off_b += (bytes + 255) & ~(size_t)255;
        return ptr;
    };
    float* h1     = (float*)alloc((size_t)N_NODES * 4 * sizeof(float));
    float* aggr1  = (float*)alloc((size_t)N_NODES * 4 * sizeof(float));
    float* hs     = (float*)alloc((size_t)N_NODES * CCH * sizeof(float));
    float* score  = (float*)alloc((size_t)N_NODES * sizeof(float));
    u64*   keys   = (u64*)alloc((size_t)MSORT * sizeof(u64));
    int*   rank   = (int*)alloc((size_t)N_NODES * sizeof(int));
    int*   noder  = (int*)alloc((size_t)N_NODES * sizeof(int));
    int*   deg    = (int*)alloc((size_t)(KKEEP + 1) * sizeof(int));
    int*   csroff = (int*)alloc((size_t)(KKEEP + 1) * sizeof(int));
    int*   cursor = (int*)alloc((size_t)KKEEP * sizeof(int));
    int*   slot   = (int*)alloc((size_t)E_EDGES * sizeof(int));
    float* aggr2  = (float*)alloc((size_t)KKEEP * CCH * sizeof(float));
    float* pooled = (float*)alloc(768 * sizeof(float));
    (void)ws_size; (void)in_sizes; (void)n_in; (void)out_size;

    hipMemsetAsync(aggr1, 0, (size_t)N_NODES * 4 * sizeof(float), stream);
    hipMemsetAsync(deg, 0, (size_t)(KKEEP + 1) * sizeof(int), stream);
    hipMemsetAsync(cursor, 0, (size_t)KKEEP * sizeof(int), stream);
    hipMemsetAsync(pooled, 0, 768 * sizeof(float), stream);

    k_h1<<<N_NODES / 4, 256, 0, stream>>>(x, Wd, bd, h1);
    k_aggr1<<<(E_EDGES + 255) / 256, 256, 0, stream>>>(ei, h1, aggr1);
    k_h_score<<<N_NODES, 128, 0, stream>>>(aggr1, h1, Wi_rel, bi, Wi_root, p, hs, score);
    k_keys<<<MSORT / 256, 256, 0, stream>>>(score, keys);

    bitonic_local<<<MSORT / 2048, 1024, 0, stream>>>(keys, 2, 2048);
    for (u32 k = 4096; k <= MSORT; k <<= 1) {
        for (u32 j = k >> 1; j >= 2048; j >>= 1)
            bitonic_global<<<MSORT / 256, 256, 0, stream>>>(keys, j, k);
        bitonic_local<<<MSORT / 2048, 1024, 0, stream>>>(keys, k, k);
    }
    k_rank<<<(N_NODES + 255) / 256, 256, 0, stream>>>(keys, rank, noder);

    k_deg<<<(E_EDGES + 255) / 256, 256, 0, stream>>>(ei, rank, deg);
    k_scan<<<1, 1024, 0, stream>>>(deg, csroff);
    k_fill<<<(E_EDGES + 255) / 256, 256, 0, stream>>>(ei, rank, csroff, cursor, slot);
    k_gather<<<(KKEEP + 3) / 4, 256, 0, stream>>>(csroff, slot, hs, aggr2);

    k_h2pool<<<(KKEEP + 31) / 32, 256, 0, stream>>>(aggr2, hs, noder,
                                                    W1_rel, b1, W1_root, pooled);
    k_out<<<1, 768, 0, stream>>>(pooled, Wo, bo, (float*)d_out);
}

// Round 6
// 993.543 us; speedup vs baseline: 2.0551x; 1.0961x over previous
//
#include <hip/hip_runtime.h>
#include <stdint.h>

// Problem constants (fixed by the reference)
#define N_NODES 100000
#define D_FEAT  128
#define E_EDGES 1600000
#define ACMC    4
#define CCH     128
#define C2CH    256
#define KKEEP   70000     // ceil(0.7 * N)
#define MSORT   131072    // 2^17 >= N, bitonic size

typedef unsigned int u32;
typedef unsigned long long u64;
typedef unsigned short u16;

__device__ __forceinline__ float gelu_exact(float v){
    return 0.5f * v * (1.0f + erff(v * 0.70710678118654752440f));
}

// ---------------- Full-graph CSR build (dst -> src list), reused twice ----------------
__global__ __launch_bounds__(256) void k_deg(const int* __restrict__ ei,
                                             int* __restrict__ deg) {
    int e = blockIdx.x * blockDim.x + threadIdx.x;
    if (e >= E_EDGES) return;
    int d = ei[E_EDGES + e];
    atomicAdd(&deg[d], 1);
}

// Exclusive scan of deg[0..N_NODES) -> off[0..N_NODES], single block of 1024 threads.
__global__ __launch_bounds__(1024) void k_scan(const int* __restrict__ deg,
                                               int* __restrict__ off) {
    const int T = 1024;
    const int chunk = (N_NODES + T - 1) / T;   // 98
    int t = threadIdx.x;
    int begin = t * chunk;
    int end = begin + chunk; if (end > N_NODES) end = N_NODES;
    int sum = 0;
    for (int i = begin; i < end; i++) sum += deg[i];
    int lane = t & 63, wid = t >> 6;
    int v = sum;
    #pragma unroll
    for (int o = 1; o < 64; o <<= 1) {
        int u = __shfl_up(v, o);
        if (lane >= o) v += u;
    }
    __shared__ int wtot[16];
    __shared__ int wbase[17];
    if (lane == 63) wtot[wid] = v;
    __syncthreads();
    if (t == 0) {
        int run = 0;
        #pragma unroll
        for (int w = 0; w < 16; w++) { wbase[w] = run; run += wtot[w]; }
        wbase[16] = run;
        off[N_NODES] = run;
    }
    __syncthreads();
    int run = wbase[wid] + (v - sum);
    for (int i = begin; i < end; i++) { off[i] = run; run += deg[i]; }
}

__global__ __launch_bounds__(256) void k_fill(const int* __restrict__ ei,
                                              const int* __restrict__ off,
                                              int* __restrict__ cursor,
                                              int* __restrict__ slot) {
    int e = blockIdx.x * blockDim.x + threadIdx.x;
    if (e >= E_EDGES) return;
    int s = ei[e], d = ei[E_EDGES + e];
    int pos = atomicAdd(&cursor[d], 1);
    slot[off[d] + pos] = s;
}

// ---------------- Stage 1: h1 = gelu(x @ Wd_root.T + bd)  [N,4] ----------------
__global__ __launch_bounds__(256) void k_h1(const float* __restrict__ x,
                                            const float* __restrict__ Wd,
                                            const float* __restrict__ bd,
                                            float* __restrict__ h1) {
    int tid = threadIdx.x;
    int wid = tid >> 6, lane = tid & 63;
    int node = blockIdx.x * 4 + wid;
    if (node >= N_NODES) return;
    const float2* xr = (const float2*)(x + (size_t)node * D_FEAT);
    float2 v = xr[lane];
    const float2* wd = (const float2*)Wd;
    float s[4];
    #pragma unroll
    for (int j = 0; j < 4; j++) {
        float2 w = wd[j * 64 + lane];
        s[j] = v.x * w.x + v.y * w.y;
    }
    #pragma unroll
    for (int off = 32; off > 0; off >>= 1) {
        #pragma unroll
        for (int j = 0; j < 4; j++) s[j] += __shfl_xor(s[j], off);
    }
    if (lane == 0) {
        float4 o;
        o.x = gelu_exact(s[0] + bd[0]);
        o.y = gelu_exact(s[1] + bd[1]);
        o.z = gelu_exact(s[2] + bd[2]);
        o.w = gelu_exact(s[3] + bd[3]);
        ((float4*)h1)[node] = o;
    }
}

// ---------------- Stage 2 (gather): aggr1[d] = sum_{src in CSR[d]} h1[src] ----------------
// Thread per dst node; h1 (1.6 MB) is L2-resident. One plain 16B store per node.
__global__ __launch_bounds__(256) void k_aggr1g(const int* __restrict__ off,
                                                const int* __restrict__ slot,
                                                const float* __restrict__ h1,
                                                float* __restrict__ aggr1) {
    int d = blockIdx.x * blockDim.x + threadIdx.x;
    if (d >= N_NODES) return;
    int i = off[d], end = off[d + 1];
    float4 acc = make_float4(0.f, 0.f, 0.f, 0.f);
    for (; i < end; i++) {
        int s = slot[i];
        float4 v = ((const float4*)h1)[s];
        acc.x += v.x; acc.y += v.y; acc.z += v.z; acc.w += v.w;
    }
    ((float4*)aggr1)[d] = acc;
}

// ---------------- Stage 3: hs = gelu(...)*score; score = tanh(h.p/||p||) ----------------
__global__ __launch_bounds__(128) void k_h_score(const float* __restrict__ aggr1,
                                                 const float* __restrict__ h1,
                                                 const float* __restrict__ Wi_rel,
                                                 const float* __restrict__ bi,
                                                 const float* __restrict__ Wi_root,
                                                 const float* __restrict__ p,
                                                 float* __restrict__ hs,
                                                 float* __restrict__ score) {
    int node = blockIdx.x;
    int c = threadIdx.x;
    float4 ag = ((const float4*)aggr1)[node];
    float4 hv = ((const float4*)h1)[node];
    float4 wr = ((const float4*)Wi_rel)[c];
    float4 wo = ((const float4*)Wi_root)[c];
    float val = ag.x * wr.x + ag.y * wr.y + ag.z * wr.z + ag.w * wr.w
              + hv.x * wo.x + hv.y * wo.y + hv.z * wo.z + hv.w * wo.w
              + bi[c];
    float g = gelu_exact(val);
    float pc = p[c];
    float hp = g * pc, pp = pc * pc;
    #pragma unroll
    for (int off = 32; off > 0; off >>= 1) {
        hp += __shfl_xor(hp, off);
        pp += __shfl_xor(pp, off);
    }
    __shared__ float sh[2], sp[2];
    __shared__ float sscore;
    int wid = c >> 6, lane = c & 63;
    if (lane == 0) { sh[wid] = hp; sp[wid] = pp; }
    __syncthreads();
    if (c == 0) {
        float H = sh[0] + sh[1], P = sp[0] + sp[1];
        float sc = tanhf(H / sqrtf(P));
        score[node] = sc;
        sscore = sc;
    }
    __syncthreads();
    hs[(size_t)node * CCH + c] = g * sscore;
}

// ---------------- Stage 4: sort keys = (~sortable(score))<<32 | idx, ascending ----------------
__global__ __launch_bounds__(256) void k_keys(const float* __restrict__ score,
                                              u64* __restrict__ keys) {
    int i = blockIdx.x * blockDim.x + threadIdx.x;
    if (i >= MSORT) return;
    if (i < N_NODES) {
        u32 u = __float_as_uint(score[i]);
        u32 asc = (u & 0x80000000u) ? ~u : (u | 0x80000000u); // monotone float->uint
        keys[i] = (((u64)(~asc)) << 32) | (u32)i;
    } else {
        keys[i] = 0xFFFFFFFFFFFFFFFFull;  // pad sorts to the end
    }
}

__global__ __launch_bounds__(1024) void bitonic_local(u64* __restrict__ keys,
                                                      u32 kLo, u32 kHi) {
    __shared__ u64 s[2048];
    u32 base = blockIdx.x * 2048;
    u32 t = threadIdx.x;
    s[t] = keys[base + t];
    s[t + 1024] = keys[base + t + 1024];
    __syncthreads();
    for (u32 k = kLo; k <= kHi; k <<= 1) {
        u32 jstart = (k >> 1) < 1024u ? (k >> 1) : 1024u;
        for (u32 j = jstart; j >= 1; j >>= 1) {
            u32 i = ((t & ~(j - 1)) << 1) | (t & (j - 1));
            u32 l = i + j;
            bool up = (((base + i) & k) == 0);
            u64 av = s[i], bv = s[l];
            if ((av > bv) == up) { s[i] = bv; s[l] = av; }
            __syncthreads();
        }
    }
    keys[base + t] = s[t];
    keys[base + t + 1024] = s[t + 1024];
}

__global__ __launch_bounds__(256) void bitonic_global(u64* __restrict__ keys,
                                                      u32 j, u32 k) {
    u32 i = blockIdx.x * blockDim.x + threadIdx.x;
    if (i >= MSORT) return;
    u32 l = i ^ j;
    if (l > i) {
        bool up = ((i & k) == 0);
        u64 av = keys[i], bv = keys[l];
        if ((av > bv) == up) { keys[i] = bv; keys[l] = av; }
    }
}

// rank[node] = sorted position; noder[pos] = node (inverse permutation)
__global__ __launch_bounds__(256) void k_rank(const u64* __restrict__ keys,
                                              int* __restrict__ rank,
                                              int* __restrict__ noder) {
    int i = blockIdx.x * blockDim.x + threadIdx.x;
    if (i >= N_NODES) return;
    u32 n = (u32)(keys[i] & 0xFFFFFFFFu);
    rank[n] = i;
    noder[i] = (int)n;
}

// ---------------- Stage 5a (gather): aggr2[rank[d]] = sum valid hs[src] ----------------
// Wave per dst node over the full CSR; filter by rank at read time (broadcast
// scalar loads of slot/rank; 512B coalesced hs rows; one plain 512B store).
__global__ __launch_bounds__(256) void k_gather(const int* __restrict__ off,
                                                const int* __restrict__ slot,
                                                const int* __restrict__ rank,
                                                const float* __restrict__ hs,
                                                float* __restrict__ aggr2) {
    int tid = threadIdx.x;
    int wid = tid >> 6, lane = tid & 63;
    int d = blockIdx.x * 4 + wid;
    if (d >= N_NODES) return;
    int rd = rank[d];
    if (rd >= KKEEP) return;
    int i = off[d], end = off[d + 1];
    float2 acc = make_float2(0.f, 0.f);
    for (; i < end; i++) {
        int s = slot[i];
        if (rank[s] < KKEEP) {
            float2 v = ((const float2*)(hs + (size_t)s * CCH))[lane];
            acc.x += v.x;
            acc.y += v.y;
        }
    }
    ((float2*)(aggr2 + (size_t)rd * CCH))[lane] = acc;
}

// ---------------- Stage 5b+6: fused GEMM over ranks + mod-3 pool ----------------
// h2[r] = gelu( [aggr2[r] | hs[noder[r]]] . [W1_rel_row | W1_root_row] + b1 )
__global__ __launch_bounds__(256) void k_h2pool(const float* __restrict__ aggr2,
                                                const float* __restrict__ hs,
                                                const int* __restrict__ noder,
                                                const float* __restrict__ W1_rel,
                                                const float* __restrict__ b1,
                                                const float* __restrict__ W1_root,
                                                float* __restrict__ pooled) {
    __shared__ float in[32][256];
    __shared__ int   snode[32];
    int tid = threadIdx.x;
    int base = blockIdx.x * 32;
    if (tid < 32) {
        int r = base + tid;
        snode[tid] = (r < KKEEP) ? noder[r] : -1;
    }
    __syncthreads();
    #pragma unroll
    for (int it = 0; it < 8; it++) {
        int idx = it * 256 + tid;        // 0..2047 == i*64 + k4
        int i = idx >> 6, k4 = idx & 63;
        int n = snode[i];
        float4 v = make_float4(0.f, 0.f, 0.f, 0.f);
        if (n >= 0) {
            if (k4 < 32) {
                v = ((const float4*)aggr2)[(size_t)(base + i) * 32 + k4];
            } else {
                v = ((const float4*)hs)[(size_t)n * 32 + (k4 - 32)];
            }
        }
        ((float4*)in)[idx] = v;
    }
    __syncthreads();

    int c2 = tid;
    float acc[32];
    #pragma unroll
    for (int i = 0; i < 32; i++) acc[i] = 0.0f;
    const float4* wrel  = (const float4*)W1_rel  + (size_t)c2 * 32;
    const float4* wroot = (const float4*)W1_root + (size_t)c2 * 32;
    #pragma unroll 1
    for (int kk = 0; kk < 32; kk++) {
        float4 w = wrel[kk];
        #pragma unroll
        for (int i = 0; i < 32; i++) {
            float4 v = ((const float4*)&in[i][0])[kk];
            acc[i] += v.x * w.x + v.y * w.y + v.z * w.z + v.w * w.w;
        }
    }
    #pragma unroll 1
    for (int kk = 0; kk < 32; kk++) {
        float4 w = wroot[kk];
        #pragma unroll
        for (int i = 0; i < 32; i++) {
            float4 v = ((const float4*)&in[i][0])[32 + kk];
            acc[i] += v.x * w.x + v.y * w.y + v.z * w.z + v.w * w.w;
        }
    }

    float bc = b1[c2];
    float p0 = 0.f, p1 = 0.f, p2 = 0.f;
    #pragma unroll
    for (int i = 0; i < 32; i++) {
        if (snode[i] >= 0) {
            float g = gelu_exact(acc[i] + bc);
            int ci = (base + i) % 3;
            if (ci == 0) p0 += g; else if (ci == 1) p1 += g; else p2 += g;
        }
    }
    if (p0 != 0.0f) atomicAdd(&pooled[0 * 256 + c2], p0);
    if (p1 != 0.0f) atomicAdd(&pooled[1 * 256 + c2], p1);
    if (p2 != 0.0f) atomicAdd(&pooled[2 * 256 + c2], p2);
}

// ---------------- Stage 7: out = (pooled/counts).flatten() @ Wo.T + bo ----------------
__global__ __launch_bounds__(768) void k_out(const float* __restrict__ pooled,
                                             const float* __restrict__ Wo,
                                             const float* __restrict__ bo,
                                             float* __restrict__ out) {
    __shared__ float red[12];
    int t = threadIdx.x;   // 768 threads
    int ci = t >> 8;
    float cnt = (ci == 0) ? 23334.0f : 23333.0f;  // #ranks == ci (mod 3), K=70000
    float acc = (pooled[t] / cnt) * Wo[t];
    #pragma unroll
    for (int off = 32; off > 0; off >>= 1) acc += __shfl_xor(acc, off);
    int wid = t >> 6, lane = t & 63;
    if (lane == 0) red[wid] = acc;
    __syncthreads();
    if (t == 0) {
        float s = 0.0f;
        #pragma unroll
        for (int w = 0; w < 12; w++) s += red[w];
        out[0] = s + bo[0];
    }
}

extern "C" void kernel_launch(void* const* d_in, const int* in_sizes, int n_in,
                              void* d_out, int out_size, void* d_ws, size_t ws_size,
                              hipStream_t stream) {
    const float* x       = (const float*)d_in[0];
    const int*   ei      = (const int*)d_in[1];
    const float* Wd      = (const float*)d_in[2];
    const float* bd      = (const float*)d_in[3];
    const float* Wi_rel  = (const float*)d_in[4];
    const float* bi      = (const float*)d_in[5];
    const float* Wi_root = (const float*)d_in[6];
    const float* p       = (const float*)d_in[7];
    const float* W1_rel  = (const float*)d_in[8];
    const float* b1      = (const float*)d_in[9];
    const float* W1_root = (const float*)d_in[10];
    const float* Wo      = (const float*)d_in[11];
    const float* bo      = (const float*)d_in[12];

    char* ws = (char*)d_ws;
    size_t off_b = 0;
    auto alloc = [&](size_t bytes) -> void* {
        void* ptr = ws + off_b;
        off_b += (bytes + 255) & ~(size_t)255;
        return ptr;
    };
    float* h1     = (float*)alloc((size_t)N_NODES * 4 * sizeof(float));
    float* aggr1  = (float*)alloc((size_t)N_NODES * 4 * sizeof(float));
    float* hs     = (float*)alloc((size_t)N_NODES * CCH * sizeof(float));
    float* score  = (float*)alloc((size_t)N_NODES * sizeof(float));
    u64*   keys   = (u64*)alloc((size_t)MSORT * sizeof(u64));
    int*   rank   = (int*)alloc((size_t)N_NODES * sizeof(int));
    int*   noder  = (int*)alloc((size_t)N_NODES * sizeof(int));
    int*   deg    = (int*)alloc((size_t)(N_NODES + 1) * sizeof(int));
    int*   csroff = (int*)alloc((size_t)(N_NODES + 1) * sizeof(int));
    int*   cursor = (int*)alloc((size_t)N_NODES * sizeof(int));
    int*   slot   = (int*)alloc((size_t)E_EDGES * sizeof(int));
    float* aggr2  = (float*)alloc((size_t)KKEEP * CCH * sizeof(float));
    float* pooled = (float*)alloc(768 * sizeof(float));
    (void)ws_size; (void)in_sizes; (void)n_in; (void)out_size;

    hipMemsetAsync(deg, 0, (size_t)(N_NODES + 1) * sizeof(int), stream);
    hipMemsetAsync(cursor, 0, (size_t)N_NODES * sizeof(int), stream);
    hipMemsetAsync(pooled, 0, 768 * sizeof(float), stream);

    // Full-graph CSR (dst -> src), rank-independent: build once, use twice.
    k_deg<<<(E_EDGES + 255) / 256, 256, 0, stream>>>(ei, deg);
    k_scan<<<1, 1024, 0, stream>>>(deg, csroff);
    k_fill<<<(E_EDGES + 255) / 256, 256, 0, stream>>>(ei, csroff, cursor, slot);

    k_h1<<<N_NODES / 4, 256, 0, stream>>>(x, Wd, bd, h1);
    k_aggr1g<<<(N_NODES + 255) / 256, 256, 0, stream>>>(csroff, slot, h1, aggr1);
    k_h_score<<<N_NODES, 128, 0, stream>>>(aggr1, h1, Wi_rel, bi, Wi_root, p, hs, score);
    k_keys<<<MSORT / 256, 256, 0, stream>>>(score, keys);

    bitonic_local<<<MSORT / 2048, 1024, 0, stream>>>(keys, 2, 2048);
    for (u32 k = 4096; k <= MSORT; k <<= 1) {
        for (u32 j = k >> 1; j >= 2048; j >>= 1)
            bitonic_global<<<MSORT / 256, 256, 0, stream>>>(keys, j, k);
        bitonic_local<<<MSORT / 2048, 1024, 0, stream>>>(keys, k, k);
    }
    k_rank<<<(N_NODES + 255) / 256, 256, 0, stream>>>(keys, rank, noder);

    k_gather<<<(N_NODES + 3) / 4, 256, 0, stream>>>(csroff, slot, rank, hs, aggr2);
    k_h2pool<<<(KKEEP + 31) / 32, 256, 0, stream>>>(aggr2, hs, noder,
                                                    W1_rel, b1, W1_root, pooled);
    k_out<<<1, 768, 0, stream>>>(pooled, Wo, bo, (float*)d_out);
}